// Round 3
// baseline (1675.600 us; speedup 1.0000x reference)
//
#include <hip/hip_runtime.h>

// ALIGNNMT gated-GCN layer, MI355X/gfx950. Round 3: fp32 correctness baseline.
// All float tensors are FP32 (per harness contract: dtype follows the reference).
// Rounds 1-2 NaN'd because fp32 buffers were read as bf16 (mantissa bits -> NaN bf16).
// Simple scalar kernels, coalesced (lane = column), fp32 atomics, m staged in outy.

__device__ __forceinline__ float sigm(float x) {
    return 1.0f / (1.0f + __expf(-x));
}

// ---------------- K1: fused node linears -> e_src, e_dst, Bh, xs ----------------
__global__ __launch_bounds__(256) void k_node_lin(
    const float* __restrict__ nf,
    const float* __restrict__ Wsg, const float* __restrict__ bsg,
    const float* __restrict__ Wdg, const float* __restrict__ bdg,
    const float* __restrict__ Wdu, const float* __restrict__ bdu,
    const float* __restrict__ Wsu, const float* __restrict__ bsu,
    float* __restrict__ esrc, float* __restrict__ edst,
    float* __restrict__ Bh, float* __restrict__ xs, int N)
{
    int i = blockIdx.x * 256 + threadIdx.x;
    if (i >= N * 64) return;
    int n = i >> 6, c = i & 63;
    const float* a = nf + (size_t)n * 64;
    float s0 = bsg[c], s1 = bdg[c], s2 = bdu[c], s3 = bsu[c];
    #pragma unroll 8
    for (int k = 0; k < 64; k++) {
        float av = a[k];                 // broadcast within wave (all lanes same n)
        s0 = fmaf(av, Wsg[k * 64 + c], s0);  // coalesced: lane c -> consecutive
        s1 = fmaf(av, Wdg[k * 64 + c], s1);
        s2 = fmaf(av, Wdu[k * 64 + c], s2);
        s3 = fmaf(av, Wsu[k * 64 + c], s3);
    }
    esrc[i] = s0; edst[i] = s1; Bh[i] = s2; xs[i] = s3;
}

// ---------------- K2: edge gate GEMM + gather + sigmoid + scatter + edge BN stats ----------------
__global__ __launch_bounds__(256) void k_edge(
    const float* __restrict__ ef, const int* __restrict__ src, const int* __restrict__ dst,
    const float* __restrict__ Weg, const float* __restrict__ beg,
    const float* __restrict__ esrc, const float* __restrict__ edst, const float* __restrict__ Bh,
    float* __restrict__ ssig, float* __restrict__ ssigh,
    float* __restrict__ mout, float* __restrict__ stat, int E)
{
    int tid = threadIdx.x;
    int stride = gridDim.x * 256;
    float sts = 0.f, stq = 0.f;
    for (int i = blockIdx.x * 256 + tid; i < E * 64; i += stride) {
        int e = i >> 6, c = i & 63;
        const float* a = ef + (size_t)e * 64;
        float m = beg[c];
        #pragma unroll 8
        for (int k = 0; k < 64; k++)
            m = fmaf(a[k], Weg[k * 64 + c], m);   // a[k] broadcast, Weg coalesced (L1-hot, 16 KB)
        int sN = src[e], dN = dst[e];
        m += esrc[(size_t)sN * 64 + c] + edst[(size_t)dN * 64 + c];
        mout[i] = m;
        sts += m; stq += m * m;
        float sg = sigm(m);
        atomicAdd(&ssig[(size_t)dN * 64 + c], sg);
        atomicAdd(&ssigh[(size_t)dN * 64 + c], sg * Bh[(size_t)sN * 64 + c]);
    }
    // block reduction: threads tid, tid+64, tid+128, tid+192 share column tid&63
    __shared__ float r1[256], r2[256];
    r1[tid] = sts; r2[tid] = stq;
    __syncthreads();
    if (tid < 64) {
        float a = r1[tid] + r1[tid + 64] + r1[tid + 128] + r1[tid + 192];
        float b = r2[tid] + r2[tid + 64] + r2[tid + 128] + r2[tid + 192];
        atomicAdd(&stat[tid], a);
        atomicAdd(&stat[64 + tid], b);
    }
}

// ---------------- K3: h = ssigh/(ssig+1e-6), x_pre = xs + h, node BN stats ----------------
__global__ __launch_bounds__(256) void k_node_agg(
    const float* __restrict__ ssig, const float* __restrict__ ssigh,
    const float* __restrict__ xs, float* __restrict__ xpre,
    float* __restrict__ stat, int N)
{
    int tid = threadIdx.x;
    int stride = gridDim.x * 256;
    float sts = 0.f, stq = 0.f;
    for (int i = blockIdx.x * 256 + tid; i < N * 64; i += stride) {
        float a = ssig[i];
        float xv = xs[i] + ssigh[i] / (fmaxf(a, 0.f) + 1e-6f);
        xpre[i] = xv;
        sts += xv; stq += xv * xv;
    }
    __shared__ float r1[256], r2[256];
    r1[tid] = sts; r2[tid] = stq;
    __syncthreads();
    if (tid < 64) {
        float a = r1[tid] + r1[tid + 64] + r1[tid + 128] + r1[tid + 192];
        float b = r2[tid] + r2[tid + 64] + r2[tid + 128] + r2[tid + 192];
        atomicAdd(&stat[128 + tid], a);
        atomicAdd(&stat[192 + tid], b);
    }
}

// ---------------- K4: finalize BN scale/shift ----------------
__global__ __launch_bounds__(128) void k_finalize(
    const float* __restrict__ stat,
    const float* __restrict__ gn, const float* __restrict__ bn,
    const float* __restrict__ ge, const float* __restrict__ be,
    float* __restrict__ scsh, int N, int E)
{
    int t = threadIdx.x;
    if (t < 64) {
        float inv = 1.0f / (float)E;
        float mean = stat[t] * inv;
        float var = fmaxf(stat[64 + t] * inv - mean * mean, 0.0f);
        float rs = rsqrtf(var + 1e-5f);
        float g = ge[t], b = be[t];
        scsh[t] = g * rs;               // edge scale
        scsh[64 + t] = b - mean * g * rs;  // edge shift
    } else {
        int c = t - 64;
        float inv = 1.0f / (float)N;
        float mean = stat[128 + c] * inv;
        float var = fmaxf(stat[192 + c] * inv - mean * mean, 0.0f);
        float rs = rsqrtf(var + 1e-5f);
        float g = gn[c], b = bn[c];
        scsh[128 + c] = g * rs;         // node scale
        scsh[192 + c] = b - mean * g * rs; // node shift
    }
}

// ---------------- K5: x_out = nf + silu(bn(x_pre)) ----------------
__global__ __launch_bounds__(256) void k_node_out(
    const float* __restrict__ nf, const float* __restrict__ xpre,
    const float* __restrict__ scsh, float* __restrict__ out, int N)
{
    int i = blockIdx.x * 256 + threadIdx.x;
    if (i >= N * 64) return;
    int c = i & 63;
    float v = xpre[i] * scsh[128 + c] + scsh[192 + c];
    out[i] = nf[i] + v * sigm(v);
}

// ---------------- K6: y_out = ef + silu(bn(m))  (in place on outy) ----------------
__global__ __launch_bounds__(256) void k_edge_out(
    const float* __restrict__ ef, const float* __restrict__ scsh,
    float* __restrict__ outy, int E)
{
    int i = blockIdx.x * 256 + threadIdx.x;
    if (i >= E * 64) return;
    int c = i & 63;
    float v = outy[i] * scsh[c] + scsh[64 + c];
    outy[i] = ef[i] + v * sigm(v);
}

extern "C" void kernel_launch(void* const* d_in, const int* in_sizes, int n_in,
                              void* d_out, int out_size, void* d_ws, size_t ws_size,
                              hipStream_t stream)
{
    const float* nf  = (const float*)d_in[0];
    const float* ef  = (const float*)d_in[1];
    const int*   src = (const int*)d_in[2];
    const int*   dst = (const int*)d_in[3];
    const float* Wsg = (const float*)d_in[4];
    const float* bsg = (const float*)d_in[5];
    const float* Wdg = (const float*)d_in[6];
    const float* bdg = (const float*)d_in[7];
    const float* Weg = (const float*)d_in[8];
    const float* beg = (const float*)d_in[9];
    const float* Wsu = (const float*)d_in[10];
    const float* bsu = (const float*)d_in[11];
    const float* Wdu = (const float*)d_in[12];
    const float* bdu = (const float*)d_in[13];
    const float* gn  = (const float*)d_in[14];
    const float* bn  = (const float*)d_in[15];
    const float* ge  = (const float*)d_in[16];
    const float* be  = (const float*)d_in[17];

    int N = in_sizes[0] / 64;
    int E = in_sizes[2];

    char* ws = (char*)d_ws;
    size_t NF = (size_t)N * 64 * 4;   // one [N,64] fp32 array, bytes
    // layout: [esrc][edst][Bh][xs][ssig][ssigh][stat 1KB][scsh 1KB][xpre]
    size_t need = 7 * NF + 2048;
    if (ws_size < need) return;

    float* esrc = (float*)(ws);
    float* edst = (float*)(ws + NF);
    float* Bh   = (float*)(ws + 2 * NF);
    float* xs   = (float*)(ws + 3 * NF);
    float* ssig = (float*)(ws + 4 * NF);
    float* ssigh= (float*)(ws + 5 * NF);
    float* stat = (float*)(ws + 6 * NF);          // 256 floats
    float* scsh = (float*)(ws + 6 * NF + 1024);   // 256 floats
    float* xpre = (float*)(ws + 6 * NF + 2048);

    float* outx = (float*)d_out;
    float* outy = outx + (size_t)N * 64;   // m staged here, finalized in place by K6

    // zero: ssig, ssigh, stat
    hipMemsetAsync(ws + 4 * NF, 0, 2 * NF + 1024, stream);

    hipLaunchKernelGGL(k_node_lin, dim3((N * 64 + 255) / 256), dim3(256), 0, stream,
                       nf, Wsg, bsg, Wdg, bdg, Wdu, bdu, Wsu, bsu,
                       esrc, edst, Bh, xs, N);
    hipLaunchKernelGGL(k_edge, dim3(1024), dim3(256), 0, stream,
                       ef, src, dst, Weg, beg, esrc, edst, Bh,
                       ssig, ssigh, outy, stat, E);
    hipLaunchKernelGGL(k_node_agg, dim3(512), dim3(256), 0, stream,
                       ssig, ssigh, xs, xpre, stat, N);
    hipLaunchKernelGGL(k_finalize, dim3(1), dim3(128), 0, stream,
                       stat, gn, bn, ge, be, scsh, N, E);
    hipLaunchKernelGGL(k_node_out, dim3((N * 64 + 255) / 256), dim3(256), 0, stream,
                       nf, xpre, scsh, outx, N);
    hipLaunchKernelGGL(k_edge_out, dim3((E * 64 + 255) / 256), dim3(256), 0, stream,
                       ef, scsh, outy, E);
}